// Round 2
// baseline (346.262 us; speedup 1.0000x reference)
//
#include <hip/hip_runtime.h>

#define NTOKEN 50257
#define NTOK_PAD 50304   // 393 * 128
#define SB 1024
#define C_LOG2PI 235.2482644909f  // 0.5 * 256 * log(2*pi)

typedef __attribute__((ext_vector_type(8))) short bf16x8;
typedef __attribute__((ext_vector_type(4))) float f32x4;

#define MFMA16(a, b, c) __builtin_amdgcn_mfma_f32_16x16x32_bf16((a), (b), (c), 0, 0, 0)

__device__ __forceinline__ unsigned short f2bf(float f) {
  unsigned int u = __float_as_uint(f);
  u += 0x7fffu + ((u >> 16) & 1u);   // round-to-nearest-even
  return (unsigned short)(u >> 16);
}
__device__ __forceinline__ float bf2f(unsigned short s) {
  return __uint_as_float(((unsigned int)s) << 16);
}

// ---------------- workspace layout (bytes) ----------------
#define HB_OFF   0u            // 1024*256*2            = 524288
#define ZB_OFF   524288u       // 50304*256*2           = 25755648
#define SPB_OFF  26279936u     // 50304*256*2 (sp / z1) = 25755648
#define HN_OFF   52035584u     // 1024*4
#define CB_OFF   52039680u     // 50304*4
#define DM_OFF   52240896u     // 256*4
#define W1B_OFF  52241920u     // 65536*2
#define W2B_OFF  52372992u     // 65536*2  (end = 52504064)

// ---------------- prep kernels ----------------
// h -> linear bf16 + row norms. grid 32 x 256 (8 threads per row, 32 rows/blk)
__global__ __launch_bounds__(256) void prep_h(const float* __restrict__ h,
                                              short* __restrict__ hb,
                                              float* __restrict__ hnorm) {
  int row = blockIdx.x * 32 + (threadIdx.x >> 3);
  int c0 = (threadIdx.x & 7) * 32;
  float ss = 0.f;
  #pragma unroll
  for (int g = 0; g < 4; ++g) {
    int c = c0 + g * 8;
    const float4* p = (const float4*)&h[row * 256 + c];
    float4 x = p[0], y = p[1];
    float v[8] = {x.x, x.y, x.z, x.w, y.x, y.y, y.z, y.w};
    bf16x8 o;
    #pragma unroll
    for (int j = 0; j < 8; ++j) { ss += v[j] * v[j]; o[j] = (short)f2bf(v[j]); }
    *(bf16x8*)&hb[row * 256 + c] = o;
  }
  ss += __shfl_xor(ss, 1); ss += __shfl_xor(ss, 2); ss += __shfl_xor(ss, 4);
  if ((threadIdx.x & 7) == 0) hnorm[row] = ss;
}

// emb -> linear bf16 zb (padded rows zeroed) + cbias init = -0.5*||z||^2 - C
__global__ __launch_bounds__(256) void prep_z(const float* __restrict__ emb,
                                              short* __restrict__ zb,
                                              float* __restrict__ cbias) {
  int row = blockIdx.x * 32 + (threadIdx.x >> 3);
  int c0 = (threadIdx.x & 7) * 32;
  bool ok = row < NTOKEN;
  float ss = 0.f;
  #pragma unroll
  for (int g = 0; g < 4; ++g) {
    int c = c0 + g * 8;
    float v[8];
    if (ok) {
      const float4* p = (const float4*)&emb[row * 256 + c];
      float4 x = p[0], y = p[1];
      v[0] = x.x; v[1] = x.y; v[2] = x.z; v[3] = x.w;
      v[4] = y.x; v[5] = y.y; v[6] = y.z; v[7] = y.w;
    } else {
      #pragma unroll
      for (int j = 0; j < 8; ++j) v[j] = 0.f;
    }
    bf16x8 o;
    #pragma unroll
    for (int j = 0; j < 8; ++j) { ss += v[j] * v[j]; o[j] = (short)f2bf(v[j]); }
    *(bf16x8*)&zb[row * 256 + c] = o;
  }
  ss += __shfl_xor(ss, 1); ss += __shfl_xor(ss, 2); ss += __shfl_xor(ss, 4);
  if ((threadIdx.x & 7) == 0) cbias[row] = -0.5f * ss - C_LOG2PI;
}

__global__ __launch_bounds__(256) void conv_w(const float* __restrict__ W1x,
                                              const float* __restrict__ W2,
                                              short* __restrict__ W1b,
                                              short* __restrict__ W2b) {
  int base = (blockIdx.x * 256 + threadIdx.x) * 4;  // grid 64 -> 65536 elems
  float4 a = *(const float4*)&W1x[base];
  short4 o1;
  o1.x = (short)f2bf(a.x); o1.y = (short)f2bf(a.y);
  o1.z = (short)f2bf(a.z); o1.w = (short)f2bf(a.w);
  *(short4*)&W1b[base] = o1;
  float4 b = *(const float4*)&W2[base];
  short4 o2;
  o2.x = (short)f2bf(b.x); o2.y = (short)f2bf(b.y);
  o2.z = (short)f2bf(b.z); o2.w = (short)f2bf(b.w);
  *(short4*)&W2b[base] = o2;
}

// dM[j] = sum_i W1x[j,i] * W2[i,j].  grid 64 x 256, one wave per j.
__global__ __launch_bounds__(256) void diag_k(const float* __restrict__ W1x,
                                              const float* __restrict__ W2,
                                              float* __restrict__ dM) {
  int j = blockIdx.x * 4 + (threadIdx.x >> 6);
  int lane = threadIdx.x & 63;
  float s = 0.f;
  #pragma unroll
  for (int t = 0; t < 4; ++t) {
    int i = lane + t * 64;
    s += W1x[j * 256 + i] * W2[i * 256 + j];
  }
  s += __shfl_xor(s, 1); s += __shfl_xor(s, 2); s += __shfl_xor(s, 4);
  s += __shfl_xor(s, 8); s += __shfl_xor(s, 16); s += __shfl_xor(s, 32);
  if (lane == 0) dM[j] = s;
}

// ---------------- CNF GEMM passes (no LDS, no barriers) ----------------
// Block: 64 token rows x 256 cols. 4 waves split cols (64 each).
// STEP 1: pre0 = A@W1^T + b1       -> store softplus(pre0); tr atomics
// STEP 2: f0  = A@W2^T + b2        -> store z1 = z0 + 0.5*f0 (aliases A!)
// STEP 3: pre1 = A@W1^T + b1+.5w1t -> tr atomics only
template <int STEP>
__global__ __launch_bounds__(256) void cnf_gemm(
    const short* __restrict__ A, const short* __restrict__ W,
    const float* __restrict__ b1, const float* __restrict__ w1t,
    const float* __restrict__ b2, const float* __restrict__ dM,
    const short* __restrict__ zb, short* __restrict__ outb,
    float* __restrict__ cbias) {
  const int lane = threadIdx.x & 63;
  const int wv = threadIdx.x >> 6;
  const int l15 = lane & 15;
  const int rg = (lane >> 4) * 4;
  const int kof = (lane >> 4) * 8;
  const int row0 = blockIdx.x * 64;
  const int cb = wv * 64;  // wave col base

  const f32x4 vzero = {0.f, 0.f, 0.f, 0.f};
  f32x4 acc[4][4];
  #pragma unroll
  for (int m = 0; m < 4; ++m)
    #pragma unroll
    for (int n = 0; n < 4; ++n) acc[m][n] = vzero;

  #pragma unroll
  for (int s = 0; s < 8; ++s) {
    int k0 = s * 32 + kof;
    bf16x8 a[4];
    #pragma unroll
    for (int m = 0; m < 4; ++m)
      a[m] = *(const bf16x8*)&A[(row0 + m * 16 + l15) * 256 + k0];
    #pragma unroll
    for (int n = 0; n < 4; ++n) {
      bf16x8 b = *(const bf16x8*)&W[(cb + n * 16 + l15) * 256 + k0];
      #pragma unroll
      for (int m = 0; m < 4; ++m) acc[m][n] = MFMA16(a[m], b, acc[m][n]);
    }
  }

  if (STEP == 1 || STEP == 3) {
    float bias[4], dm[4];
    #pragma unroll
    for (int n = 0; n < 4; ++n) {
      int col = cb + n * 16 + l15;
      bias[n] = (STEP == 1) ? b1[col] : (b1[col] + 0.5f * w1t[col]);
      dm[n] = dM[col];
    }
    #pragma unroll
    for (int m = 0; m < 4; ++m)
      #pragma unroll
      for (int r = 0; r < 4; ++r) {
        int token = row0 + m * 16 + rg + r;
        float p = 0.f;
        #pragma unroll
        for (int n = 0; n < 4; ++n) {
          float pre = acc[m][n][r] + bias[n];
          float e = __expf(-fabsf(pre));
          float rc = __fdividef(1.f, 1.f + e);
          float sg = (pre >= 0.f) ? rc : e * rc;
          p += sg * dm[n];
          if (STEP == 1) {
            float sp = fmaxf(pre, 0.f) + __logf(1.f + e);
            outb[token * 256 + cb + n * 16 + l15] = (short)f2bf(sp);
          }
        }
        p += __shfl_xor(p, 1); p += __shfl_xor(p, 2);
        p += __shfl_xor(p, 4); p += __shfl_xor(p, 8);
        if (l15 == 0) atomicAdd(&cbias[token], 0.5f * p);
      }
  } else {  // STEP 2
    float b2v[4];
    #pragma unroll
    for (int n = 0; n < 4; ++n) b2v[n] = b2[cb + n * 16 + l15];
    __syncthreads();  // outb aliases A: all waves must finish reading A rows
    #pragma unroll
    for (int m = 0; m < 4; ++m)
      #pragma unroll
      for (int n = 0; n < 4; ++n)
        #pragma unroll
        for (int r = 0; r < 4; ++r) {
          int token = row0 + m * 16 + rg + r;
          int col = cb + n * 16 + l15;
          float f = acc[m][n][r] + b2v[n];
          float z0v = bf2f((unsigned short)zb[token * 256 + col]);
          outb[token * 256 + col] = (short)f2bf(z0v + 0.5f * f);
        }
  }
}

// ---------------- big log-prob GEMM (no LDS) ----------------
// Tile 128 h-rows x 128 tokens; 4 waves in 2x2; A=hb (L2-resident),
// B=zb streamed. XCD-chunked bid swizzle: each XCD walks 8 row-tiles of a
// token-col before advancing -> z tile fetched once per XCD from HBM.
__global__ __launch_bounds__(256) void logp_kernel(
    const short* __restrict__ hb, const short* __restrict__ zb,
    const float* __restrict__ hnorm, const float* __restrict__ cbias,
    float* __restrict__ out) {
  const int bid = blockIdx.x;                 // 3144 = 393 cols * 8 rows
  const int l = (bid & 7) * 393 + (bid >> 3); // contiguous chunk per XCD
  const int tc = l >> 3;                      // token-col tile [0,393)
  const int trr = l & 7;                      // h-row tile [0,8)

  const int lane = threadIdx.x & 63;
  const int wv = threadIdx.x >> 6;
  const int l15 = lane & 15;
  const int rg = (lane >> 4) * 4;
  const int kof = (lane >> 4) * 8;
  const int wr = wv >> 1, wc = wv & 1;

  const f32x4 vzero = {0.f, 0.f, 0.f, 0.f};
  f32x4 acc[4][4];
  #pragma unroll
  for (int m = 0; m < 4; ++m)
    #pragma unroll
    for (int n = 0; n < 4; ++n) acc[m][n] = vzero;

  const int arow0 = trr * 128 + wr * 64;
  const int brow0 = tc * 128 + wc * 64;
  #pragma unroll
  for (int s = 0; s < 8; ++s) {
    int k0 = s * 32 + kof;
    bf16x8 a[4];
    #pragma unroll
    for (int m = 0; m < 4; ++m)
      a[m] = *(const bf16x8*)&hb[(arow0 + m * 16 + l15) * 256 + k0];
    #pragma unroll
    for (int n = 0; n < 4; ++n) {
      bf16x8 b = *(const bf16x8*)&zb[(brow0 + n * 16 + l15) * 256 + k0];
      #pragma unroll
      for (int m = 0; m < 4; ++m) acc[m][n] = MFMA16(a[m], b, acc[m][n]);
    }
  }

  // out[i, token] = dot - 0.5*hnorm[i] + cbias[token]
  #pragma unroll
  for (int n = 0; n < 4; ++n) {
    int token = brow0 + n * 16 + l15;
    bool ok = token < NTOKEN;
    float cbv = ok ? cbias[token] : 0.f;
    #pragma unroll
    for (int m = 0; m < 4; ++m) {
      int i0 = arow0 + m * 16 + rg;
      #pragma unroll
      for (int r = 0; r < 4; ++r) {
        if (ok) {
          out[(size_t)(i0 + r) * NTOKEN + token] =
              acc[m][n][r] - 0.5f * hnorm[i0 + r] + cbv;
        }
      }
    }
  }
}

// ---------------- launcher ----------------
extern "C" void kernel_launch(void* const* d_in, const int* in_sizes, int n_in,
                              void* d_out, int out_size, void* d_ws, size_t ws_size,
                              hipStream_t stream) {
  const float* h   = (const float*)d_in[0];
  const float* emb = (const float*)d_in[1];
  const float* W1x = (const float*)d_in[2];
  const float* w1t = (const float*)d_in[3];
  const float* b1  = (const float*)d_in[4];
  const float* W2  = (const float*)d_in[5];
  const float* b2  = (const float*)d_in[6];
  float* out = (float*)d_out;

  char* ws = (char*)d_ws;
  short* hb    = (short*)(ws + HB_OFF);
  short* zb    = (short*)(ws + ZB_OFF);
  short* spb   = (short*)(ws + SPB_OFF);   // sp, then overwritten by z1
  float* hnorm = (float*)(ws + HN_OFF);
  float* cbias = (float*)(ws + CB_OFF);
  float* dM    = (float*)(ws + DM_OFF);
  short* W1b   = (short*)(ws + W1B_OFF);
  short* W2b   = (short*)(ws + W2B_OFF);

  prep_h<<<SB / 32, 256, 0, stream>>>(h, hb, hnorm);
  conv_w<<<64, 256, 0, stream>>>(W1x, W2, W1b, W2b);
  diag_k<<<64, 256, 0, stream>>>(W1x, W2, dM);
  prep_z<<<NTOK_PAD / 32, 256, 0, stream>>>(emb, zb, cbias);

  // step 1: pre0 -> sp, tr0
  cnf_gemm<1><<<NTOK_PAD / 64, 256, 0, stream>>>(zb, W1b, b1, w1t, b2, dM, zb,
                                                 spb, cbias);
  // step 2: f0 -> z1 (in place over sp)
  cnf_gemm<2><<<NTOK_PAD / 64, 256, 0, stream>>>(spb, W2b, b1, w1t, b2, dM, zb,
                                                 spb, cbias);
  // step 3: pre1 -> tr1
  cnf_gemm<3><<<NTOK_PAD / 64, 256, 0, stream>>>(spb, W1b, b1, w1t, b2, dM, zb,
                                                 spb, cbias);

  logp_kernel<<<393 * 8, 256, 0, stream>>>(hb, zb, hnorm, cbias, out);
}

// Round 3
// 232.123 us; speedup vs baseline: 1.4917x; 1.4917x over previous
//
#include <hip/hip_runtime.h>

#define NTOKEN 50257
#define NTOK_PAD 50304   // 393 * 128
#define SB 1024
#define C_LOG2PI 235.2482644909f  // 0.5 * 256 * log(2*pi)

typedef __attribute__((ext_vector_type(8))) short bf16x8;
typedef __attribute__((ext_vector_type(4))) float f32x4;
typedef float f32x4u __attribute__((ext_vector_type(4), aligned(4)));

#define MFMA16(a, b, c) __builtin_amdgcn_mfma_f32_16x16x32_bf16((a), (b), (c), 0, 0, 0)

__device__ __forceinline__ unsigned short f2bf(float f) {
  unsigned int u = __float_as_uint(f);
  u += 0x7fffu + ((u >> 16) & 1u);   // round-to-nearest-even
  return (unsigned short)(u >> 16);
}
__device__ __forceinline__ float bf2f(unsigned short s) {
  return __uint_as_float(((unsigned int)s) << 16);
}
__device__ __forceinline__ void gload16(const void* g, void* l) {
  __builtin_amdgcn_global_load_lds(
      (const __attribute__((address_space(1))) unsigned int*)g,
      (__attribute__((address_space(3))) unsigned int*)l, 16, 0, 0);
}

// ---------------- workspace layout (bytes) ----------------
#define HB_OFF   0u            // 1024*256*2  = 524288
#define ZB_OFF   524288u       // 50304*256*2 = 25755648 (pre-swizzled)
#define HN_OFF   26279936u     // 1024*4
#define CB_OFF   26284032u     // 50304*4
#define DM_OFF   26485248u     // 256*4
#define W1B_OFF  26486272u     // 65536*2
#define W2B_OFF  26617344u     // 65536*2  (end = 26748416)

// ---------------- prep kernels ----------------
// h -> linear bf16 + row norms
__global__ __launch_bounds__(256) void prep_h(const float* __restrict__ h,
                                              short* __restrict__ hb,
                                              float* __restrict__ hnorm) {
  int row = blockIdx.x * 32 + (threadIdx.x >> 3);
  int c0 = (threadIdx.x & 7) * 32;
  float ss = 0.f;
  #pragma unroll
  for (int g = 0; g < 4; ++g) {
    int c = c0 + g * 8;
    const float4* p = (const float4*)&h[row * 256 + c];
    float4 x = p[0], y = p[1];
    float v[8] = {x.x, x.y, x.z, x.w, y.x, y.y, y.z, y.w};
    bf16x8 o;
    #pragma unroll
    for (int j = 0; j < 8; ++j) { ss += v[j] * v[j]; o[j] = (short)f2bf(v[j]); }
    *(bf16x8*)&hb[row * 256 + c] = o;
  }
  ss += __shfl_xor(ss, 1); ss += __shfl_xor(ss, 2); ss += __shfl_xor(ss, 4);
  if ((threadIdx.x & 7) == 0) hnorm[row] = ss;
}

// emb -> PRE-SWIZZLED bf16 zb (8-elem group g stored at g^(row&7)) + cbias init
__global__ __launch_bounds__(256) void prep_z(const float* __restrict__ emb,
                                              short* __restrict__ zb,
                                              float* __restrict__ cbias) {
  int row = blockIdx.x * 32 + (threadIdx.x >> 3);
  int c0 = (threadIdx.x & 7) * 32;
  bool ok = row < NTOKEN;
  float ss = 0.f;
  #pragma unroll
  for (int g = 0; g < 4; ++g) {
    int c = c0 + g * 8;
    float v[8];
    if (ok) {
      const float4* p = (const float4*)&emb[row * 256 + c];
      float4 x = p[0], y = p[1];
      v[0] = x.x; v[1] = x.y; v[2] = x.z; v[3] = x.w;
      v[4] = y.x; v[5] = y.y; v[6] = y.z; v[7] = y.w;
    } else {
      #pragma unroll
      for (int j = 0; j < 8; ++j) v[j] = 0.f;
    }
    bf16x8 o;
    #pragma unroll
    for (int j = 0; j < 8; ++j) { ss += v[j] * v[j]; o[j] = (short)f2bf(v[j]); }
    int blk = (c >> 3) ^ (row & 7);
    *(bf16x8*)&zb[(size_t)row * 256 + blk * 8] = o;
  }
  ss += __shfl_xor(ss, 1); ss += __shfl_xor(ss, 2); ss += __shfl_xor(ss, 4);
  if ((threadIdx.x & 7) == 0) cbias[row] = -0.5f * ss - C_LOG2PI;
}

__global__ __launch_bounds__(256) void conv_w(const float* __restrict__ W1x,
                                              const float* __restrict__ W2,
                                              short* __restrict__ W1b,
                                              short* __restrict__ W2b) {
  int base = (blockIdx.x * 256 + threadIdx.x) * 4;
  float4 a = *(const float4*)&W1x[base];
  short4 o1;
  o1.x = (short)f2bf(a.x); o1.y = (short)f2bf(a.y);
  o1.z = (short)f2bf(a.z); o1.w = (short)f2bf(a.w);
  *(short4*)&W1b[base] = o1;
  float4 b = *(const float4*)&W2[base];
  short4 o2;
  o2.x = (short)f2bf(b.x); o2.y = (short)f2bf(b.y);
  o2.z = (short)f2bf(b.z); o2.w = (short)f2bf(b.w);
  *(short4*)&W2b[base] = o2;
}

// dM[j] = sum_i W1x[j,i] * W2[i,j]
__global__ __launch_bounds__(256) void diag_k(const float* __restrict__ W1x,
                                              const float* __restrict__ W2,
                                              float* __restrict__ dM) {
  int j = blockIdx.x * 4 + (threadIdx.x >> 6);
  int lane = threadIdx.x & 63;
  float s = 0.f;
  #pragma unroll
  for (int t = 0; t < 4; ++t) {
    int i = lane + t * 64;
    s += W1x[j * 256 + i] * W2[i * 256 + j];
  }
  s += __shfl_xor(s, 1); s += __shfl_xor(s, 2); s += __shfl_xor(s, 4);
  s += __shfl_xor(s, 8); s += __shfl_xor(s, 16); s += __shfl_xor(s, 32);
  if (lane == 0) dM[j] = s;
}

// ---------------- fused CNF ----------------
// A is a 64x256 LDS tile, rows XOR-swizzled in 8-elem groups; W is global
// (linear). Wave covers all 64 rows x 64 cols (cb base).
__device__ __forceinline__ void mm64(const short* A, const short* W, int l15,
                                     int kof, int cb, f32x4 acc[4][4]) {
  const f32x4 vz = {0.f, 0.f, 0.f, 0.f};
  #pragma unroll
  for (int m = 0; m < 4; ++m)
    #pragma unroll
    for (int n = 0; n < 4; ++n) acc[m][n] = vz;
  #pragma unroll
  for (int s = 0; s < 8; ++s) {
    int k0 = s * 32 + kof;
    int ks = k0 ^ ((l15 & 7) << 3);
    bf16x8 a[4];
    #pragma unroll
    for (int m = 0; m < 4; ++m)
      a[m] = *(const bf16x8*)&A[(m * 16 + l15) * 256 + ks];
    #pragma unroll
    for (int n = 0; n < 4; ++n) {
      bf16x8 b = *(const bf16x8*)&W[(cb + n * 16 + l15) * 256 + k0];
      #pragma unroll
      for (int m = 0; m < 4; ++m) acc[m][n] = MFMA16(a[m], b, acc[m][n]);
    }
  }
}

__global__ __launch_bounds__(256) void cnf_fused(
    const short* __restrict__ zb, const short* __restrict__ W1b,
    const short* __restrict__ W2b, const float* __restrict__ dM,
    const float* __restrict__ w1t, const float* __restrict__ b1,
    const float* __restrict__ b2, float* __restrict__ cbias) {
  __shared__ short z0t[64 * 256];   // 32 KB: z0, then z1
  __shared__ short spt[64 * 256];   // 32 KB: softplus(pre0)
  __shared__ float trs[4][64];
  const int tid = threadIdx.x;
  const int lane = tid & 63, wv = tid >> 6;
  const int l15 = lane & 15, rg = (lane >> 4) * 4, kof = (lane >> 4) * 8;
  const int cb = wv * 64;
  const int tokbase = blockIdx.x * 64;

  // stage z0 tile (pre-swizzled rows; linear 32 KB copy)
  {
    const char* src = (const char*)(zb + (size_t)tokbase * 256);
    char* dst = (char*)z0t;
    #pragma unroll
    for (int it = 0; it < 8; ++it) {
      int uoff = wv * 8192 + it * 1024;
      gload16(src + uoff + lane * 16, dst + uoff);
    }
  }
  __syncthreads();

  f32x4 acc[4][4];

  // ---- pass A: pre0 = z0@W1^T + b1; sp -> spt; tr0 partial ----
  mm64(z0t, W1b, l15, kof, cb, acc);
  {
    float bias[4], dm[4];
    #pragma unroll
    for (int n = 0; n < 4; ++n) {
      int col = cb + n * 16 + l15;
      bias[n] = b1[col];
      dm[n] = dM[col];
    }
    #pragma unroll
    for (int m = 0; m < 4; ++m)
      #pragma unroll
      for (int r = 0; r < 4; ++r) {
        int trow = m * 16 + rg + r;
        float p = 0.f;
        #pragma unroll
        for (int n = 0; n < 4; ++n) {
          float pre = acc[m][n][r] + bias[n];
          float e = __expf(-fabsf(pre));
          float rc = __fdividef(1.f, 1.f + e);
          p += ((pre >= 0.f) ? rc : e * rc) * dm[n];
          float sp = fmaxf(pre, 0.f) + __logf(1.f + e);
          int col = cb + n * 16 + l15;
          spt[trow * 256 + (col ^ ((trow & 7) << 3))] = (short)f2bf(sp);
        }
        p += __shfl_xor(p, 1); p += __shfl_xor(p, 2);
        p += __shfl_xor(p, 4); p += __shfl_xor(p, 8);
        if (l15 == 0) trs[wv][trow] = p;
      }
  }
  __syncthreads();

  // ---- pass B: f0 = sp@W2^T + b2; z1 = z0 + 0.5*f0 (into z0t) ----
  mm64(spt, W2b, l15, kof, cb, acc);
  {
    float b2v[4];
    #pragma unroll
    for (int n = 0; n < 4; ++n) b2v[n] = b2[cb + n * 16 + l15];
    #pragma unroll
    for (int m = 0; m < 4; ++m)
      #pragma unroll
      for (int n = 0; n < 4; ++n)
        #pragma unroll
        for (int r = 0; r < 4; ++r) {
          int trow = m * 16 + rg + r;
          int col = cb + n * 16 + l15;
          int idx = trow * 256 + (col ^ ((trow & 7) << 3));
          float f = acc[m][n][r] + b2v[n];
          float z0v = bf2f((unsigned short)z0t[idx]);
          z0t[idx] = (short)f2bf(z0v + 0.5f * f);  // cell owned by this lane
        }
  }
  __syncthreads();

  // ---- pass C: pre1 = z1@W1^T + b1 + 0.5*w1t; tr1 partial ----
  mm64(z0t, W1b, l15, kof, cb, acc);
  {
    float bias[4], dm[4];
    #pragma unroll
    for (int n = 0; n < 4; ++n) {
      int col = cb + n * 16 + l15;
      bias[n] = b1[col] + 0.5f * w1t[col];
      dm[n] = dM[col];
    }
    #pragma unroll
    for (int m = 0; m < 4; ++m)
      #pragma unroll
      for (int r = 0; r < 4; ++r) {
        int trow = m * 16 + rg + r;
        float p = 0.f;
        #pragma unroll
        for (int n = 0; n < 4; ++n) {
          float pre = acc[m][n][r] + bias[n];
          float e = __expf(-fabsf(pre));
          float rc = __fdividef(1.f, 1.f + e);
          p += ((pre >= 0.f) ? rc : e * rc) * dm[n];
        }
        p += __shfl_xor(p, 1); p += __shfl_xor(p, 2);
        p += __shfl_xor(p, 4); p += __shfl_xor(p, 8);
        if (l15 == 0) trs[wv][trow] += p;
      }
  }
  __syncthreads();

  if (tid < 64) {
    float t = trs[0][tid] + trs[1][tid] + trs[2][tid] + trs[3][tid];
    cbias[tokbase + tid] += 0.5f * t;
  }
}

// ---------------- big log-prob GEMM ----------------
// Block: 128 h-rows x 128 tokens. rr = bid&7 (row-stripe pinned to XCD under
// round-robin dispatch), tc = bid>>3 walks tokens L->R per XCD: write-boundary
// lines merge in one L2, h-stripe is L1/L2-resident, zb shared via L3.
// B staged via global_load_lds (pre-swizzled rows); epilogue transposes
// through wave-private LDS (overlaid on Bz) to emit float4 row stores.
__global__ __launch_bounds__(256) void logp_kernel(
    const short* __restrict__ hb, const short* __restrict__ zb,
    const float* __restrict__ hnorm, const float* __restrict__ cbias,
    float* __restrict__ out) {
  __shared__ char smem[65536];
  short* Bz = (short*)smem;
  const int bid = blockIdx.x;   // 3144 = 393 * 8
  const int rr = bid & 7;
  const int tc = bid >> 3;

  const int tid = threadIdx.x;
  const int lane = tid & 63, wv = tid >> 6;
  const int l15 = lane & 15, rg = (lane >> 4) * 4, kof = (lane >> 4) * 8;
  const int wr = wv >> 1, wc = wv & 1;

  // stage B tile (tokens tc*128..+128): 64 KB linear copy
  {
    const char* bsrc = (const char*)(zb + (size_t)tc * 128 * 256);
    #pragma unroll
    for (int it = 0; it < 16; ++it) {
      int uoff = wv * 16384 + it * 1024;
      gload16(bsrc + uoff + lane * 16, smem + uoff);
    }
  }
  __syncthreads();

  const f32x4 vz = {0.f, 0.f, 0.f, 0.f};
  f32x4 acc[4][4];
  #pragma unroll
  for (int m = 0; m < 4; ++m)
    #pragma unroll
    for (int n = 0; n < 4; ++n) acc[m][n] = vz;

  const int arow0 = rr * 128 + wr * 64;
  #pragma unroll
  for (int s = 0; s < 8; ++s) {
    int k0 = s * 32 + kof;
    int ks = k0 ^ ((l15 & 7) << 3);
    bf16x8 a[4];
    #pragma unroll
    for (int m = 0; m < 4; ++m)
      a[m] = *(const bf16x8*)&hb[(arow0 + m * 16 + l15) * 256 + k0];  // linear
    #pragma unroll
    for (int n = 0; n < 4; ++n) {
      bf16x8 b = *(const bf16x8*)&Bz[(wc * 64 + n * 16 + l15) * 256 + ks];
      #pragma unroll
      for (int m = 0; m < 4; ++m) acc[m][n] = MFMA16(a[m], b, acc[m][n]);
    }
  }
  __syncthreads();  // all waves done reading Bz; overlay transpose patches

  // wave-private 16x68 f32 patch (4352 B each)
  float* patch = (float*)(smem + wv * 4352);
  const int l4 = lane & 15, lr4 = lane >> 4;
  #pragma unroll
  for (int m = 0; m < 4; ++m) {
    #pragma unroll
    for (int n = 0; n < 4; ++n)
      #pragma unroll
      for (int r = 0; r < 4; ++r)
        patch[(rg + r) * 68 + n * 16 + l15] = acc[m][n][r];
    asm volatile("s_waitcnt lgkmcnt(0)" ::: "memory");
    #pragma unroll
    for (int q = 0; q < 4; ++q) {
      int lrow = q * 4 + lr4;
      int gr = rr * 128 + wr * 64 + m * 16 + lrow;
      int gt = tc * 128 + wc * 64 + l4 * 4;
      f32x4 v = *(const f32x4*)&patch[lrow * 68 + l4 * 4];
      float hn = hnorm[gr];
      f32x4 cb4 = *(const f32x4*)&cbias[gt];
      #pragma unroll
      for (int c = 0; c < 4; ++c) v[c] += cb4[c] - 0.5f * hn;
      float* op = out + (size_t)gr * NTOKEN + gt;
      if (gt + 4 <= NTOKEN) {
        *(f32x4u*)op = v;
      } else {
        #pragma unroll
        for (int c = 0; c < 4; ++c)
          if (gt + c < NTOKEN) op[c] = v[c];
      }
    }
    asm volatile("s_waitcnt lgkmcnt(0)" ::: "memory");
  }
}

// ---------------- launcher ----------------
extern "C" void kernel_launch(void* const* d_in, const int* in_sizes, int n_in,
                              void* d_out, int out_size, void* d_ws, size_t ws_size,
                              hipStream_t stream) {
  const float* h   = (const float*)d_in[0];
  const float* emb = (const float*)d_in[1];
  const float* W1x = (const float*)d_in[2];
  const float* w1t = (const float*)d_in[3];
  const float* b1  = (const float*)d_in[4];
  const float* W2  = (const float*)d_in[5];
  const float* b2  = (const float*)d_in[6];
  float* out = (float*)d_out;

  char* ws = (char*)d_ws;
  short* hb    = (short*)(ws + HB_OFF);
  short* zb    = (short*)(ws + ZB_OFF);
  float* hnorm = (float*)(ws + HN_OFF);
  float* cbias = (float*)(ws + CB_OFF);
  float* dM    = (float*)(ws + DM_OFF);
  short* W1b   = (short*)(ws + W1B_OFF);
  short* W2b   = (short*)(ws + W2B_OFF);

  prep_h<<<SB / 32, 256, 0, stream>>>(h, hb, hnorm);
  conv_w<<<64, 256, 0, stream>>>(W1x, W2, W1b, W2b);
  diag_k<<<64, 256, 0, stream>>>(W1x, W2, dM);
  prep_z<<<NTOK_PAD / 32, 256, 0, stream>>>(emb, zb, cbias);
  cnf_fused<<<NTOK_PAD / 64, 256, 0, stream>>>(zb, W1b, W2b, dM, w1t, b1, b2,
                                               cbias);
  logp_kernel<<<393 * 8, 256, 0, stream>>>(hb, zb, hnorm, cbias, out);
}

// Round 4
// 197.431 us; speedup vs baseline: 1.7538x; 1.1757x over previous
//
#include <hip/hip_runtime.h>

#define NTOKEN 50257
#define NTOK_PAD 50304   // 786 * 64
#define SB 1024
#define C_LOG2PI 235.2482644909f  // 0.5 * 256 * log(2*pi)

typedef __attribute__((ext_vector_type(8))) short bf16x8;
typedef __attribute__((ext_vector_type(4))) short s16x4;
typedef __attribute__((ext_vector_type(4))) float f32x4;
typedef float f32x4u __attribute__((ext_vector_type(4), aligned(4)));

#define MFMA16(a, b, c) __builtin_amdgcn_mfma_f32_16x16x32_bf16((a), (b), (c), 0, 0, 0)

__device__ __forceinline__ unsigned short f2bf(float f) {
  unsigned int u = __float_as_uint(f);
  u += 0x7fffu + ((u >> 16) & 1u);   // round-to-nearest-even
  return (unsigned short)(u >> 16);
}
__device__ __forceinline__ float bf2f(unsigned short s) {
  return __uint_as_float(((unsigned int)s) << 16);
}
__device__ __forceinline__ void gload16(const void* g, void* l) {
  __builtin_amdgcn_global_load_lds(
      (const __attribute__((address_space(1))) unsigned int*)g,
      (__attribute__((address_space(3))) unsigned int*)l, 16, 0, 0);
}

// ---------------- workspace layout (bytes) ----------------
#define HB_OFF   0u            // 1024*256*2  = 524288 (linear)
#define ZB_OFF   524288u       // 50304*256*2 = 25755648 (pre-swizzled rows)
#define HN_OFF   26279936u     // 1024*4
#define CB_OFF   26284032u     // 50304*4
#define DM_OFF   26485248u     // 256*4
#define W1B_OFF  26486272u     // 65536*2
#define W2B_OFF  26617344u     // 65536*2  (end = 26748416)

// ---------------- fused prep ----------------
// grid = 32 (h) + 64 (conv_w) + 64 (diag) + 1572 (z) = 1732 blocks x 256
__global__ __launch_bounds__(256) void prep_all(
    const float* __restrict__ h, const float* __restrict__ emb,
    const float* __restrict__ W1x, const float* __restrict__ W2,
    short* __restrict__ hb, float* __restrict__ hnorm,
    short* __restrict__ zb, float* __restrict__ cbias,
    short* __restrict__ W1b, short* __restrict__ W2b,
    float* __restrict__ dM) {
  const int bid = blockIdx.x;
  const int tid = threadIdx.x;
  if (bid < 32) {
    // ---- h -> linear bf16 + norms ----
    int row = bid * 32 + (tid >> 3);
    int c0 = (tid & 7) * 32;
    float ss = 0.f;
    #pragma unroll
    for (int g = 0; g < 4; ++g) {
      int c = c0 + g * 8;
      const float4* p = (const float4*)&h[row * 256 + c];
      float4 x = p[0], y = p[1];
      float v[8] = {x.x, x.y, x.z, x.w, y.x, y.y, y.z, y.w};
      bf16x8 o;
      #pragma unroll
      for (int j = 0; j < 8; ++j) { ss += v[j] * v[j]; o[j] = (short)f2bf(v[j]); }
      *(bf16x8*)&hb[row * 256 + c] = o;
    }
    ss += __shfl_xor(ss, 1); ss += __shfl_xor(ss, 2); ss += __shfl_xor(ss, 4);
    if ((tid & 7) == 0) hnorm[row] = ss;
  } else if (bid < 96) {
    // ---- W1x, W2 -> bf16 ----
    int base = ((bid - 32) * 256 + tid) * 4;
    float4 a = *(const float4*)&W1x[base];
    short4 o1;
    o1.x = (short)f2bf(a.x); o1.y = (short)f2bf(a.y);
    o1.z = (short)f2bf(a.z); o1.w = (short)f2bf(a.w);
    *(short4*)&W1b[base] = o1;
    float4 b = *(const float4*)&W2[base];
    short4 o2;
    o2.x = (short)f2bf(b.x); o2.y = (short)f2bf(b.y);
    o2.z = (short)f2bf(b.z); o2.w = (short)f2bf(b.w);
    *(short4*)&W2b[base] = o2;
  } else if (bid < 160) {
    // ---- dM[j] = sum_i W1x[j,i] * W2[i,j] ----
    int j = (bid - 96) * 4 + (tid >> 6);
    int lane = tid & 63;
    float s = 0.f;
    #pragma unroll
    for (int t = 0; t < 4; ++t) {
      int i = lane + t * 64;
      s += W1x[j * 256 + i] * W2[i * 256 + j];
    }
    s += __shfl_xor(s, 1); s += __shfl_xor(s, 2); s += __shfl_xor(s, 4);
    s += __shfl_xor(s, 8); s += __shfl_xor(s, 16); s += __shfl_xor(s, 32);
    if (lane == 0) dM[j] = s;
  } else {
    // ---- emb -> pre-swizzled bf16 zb + cbias init ----
    int row = (bid - 160) * 32 + (tid >> 3);
    int c0 = (tid & 7) * 32;
    bool ok = row < NTOKEN;
    float ss = 0.f;
    #pragma unroll
    for (int g = 0; g < 4; ++g) {
      int c = c0 + g * 8;
      float v[8];
      if (ok) {
        const float4* p = (const float4*)&emb[(size_t)row * 256 + c];
        float4 x = p[0], y = p[1];
        v[0] = x.x; v[1] = x.y; v[2] = x.z; v[3] = x.w;
        v[4] = y.x; v[5] = y.y; v[6] = y.z; v[7] = y.w;
      } else {
        #pragma unroll
        for (int j = 0; j < 8; ++j) v[j] = 0.f;
      }
      bf16x8 o;
      #pragma unroll
      for (int j = 0; j < 8; ++j) { ss += v[j] * v[j]; o[j] = (short)f2bf(v[j]); }
      int blk = (c >> 3) ^ (row & 7);
      *(bf16x8*)&zb[(size_t)row * 256 + blk * 8] = o;
    }
    ss += __shfl_xor(ss, 1); ss += __shfl_xor(ss, 2); ss += __shfl_xor(ss, 4);
    if ((tid & 7) == 0) cbias[row] = -0.5f * ss - C_LOG2PI;
  }
}

// ---------------- fused CNF (operand-swapped MFMA) ----------------
// accT[m][n] = MFMA16(Wfrag[m], Tfrag[n]) -> D[wcol][token]:
//   wcol = cb + m*16 + rg + r (CONTIGUOUS in r!), token = n*16 + l15.
// T = LDS tile, rows = tokens (XOR-swizzled 16B groups); W = global, linear.
__device__ __forceinline__ void mmT(const short* T, const short* __restrict__ W,
                                    int l15, int kof, int cb, f32x4 acc[4][4]) {
  const f32x4 vz = {0.f, 0.f, 0.f, 0.f};
  #pragma unroll
  for (int m = 0; m < 4; ++m)
    #pragma unroll
    for (int n = 0; n < 4; ++n) acc[m][n] = vz;
  #pragma unroll
  for (int s = 0; s < 8; ++s) {
    int k0 = s * 32 + kof;
    int ks = k0 ^ ((l15 & 7) << 3);
    bf16x8 w[4], z[4];
    #pragma unroll
    for (int m = 0; m < 4; ++m)
      w[m] = *(const bf16x8*)&W[(cb + m * 16 + l15) * 256 + k0];
    #pragma unroll
    for (int n = 0; n < 4; ++n)
      z[n] = *(const bf16x8*)&T[(n * 16 + l15) * 256 + ks];
    #pragma unroll
    for (int m = 0; m < 4; ++m)
      #pragma unroll
      for (int n = 0; n < 4; ++n) acc[m][n] = MFMA16(w[m], z[n], acc[m][n]);
  }
}

__global__ __launch_bounds__(256) void cnf_fused(
    const short* __restrict__ zb, const short* __restrict__ W1b,
    const short* __restrict__ W2b, const float* __restrict__ dM,
    const float* __restrict__ w1t, const float* __restrict__ b1,
    const float* __restrict__ b2, float* __restrict__ cbias) {
  __shared__ short z0t[64 * 256];   // 32 KB: z0, then z1
  __shared__ short spt[64 * 256];   // 32 KB: softplus(pre0)
  __shared__ float trs[4][64];
  const int tid = threadIdx.x;
  const int lane = tid & 63, wv = tid >> 6;
  const int l15 = lane & 15, rg = (lane >> 4) * 4, kof = (lane >> 4) * 8;
  const int cb = wv * 64;
  const int tokbase = blockIdx.x * 64;

  // stage z0 tile (pre-swizzled rows; linear 32 KB copy)
  {
    const char* src = (const char*)(zb + (size_t)tokbase * 256);
    char* dst = (char*)z0t;
    #pragma unroll
    for (int it = 0; it < 8; ++it) {
      int uoff = wv * 8192 + it * 1024;
      gload16(src + uoff + lane * 16, dst + uoff);
    }
  }
  // per-lane wcol-quad biases (vector loads; lanes with same rg broadcast)
  f32x4 b1v[4], dmv[4];
  #pragma unroll
  for (int m = 0; m < 4; ++m) {
    b1v[m] = *(const f32x4*)&b1[cb + m * 16 + rg];
    dmv[m] = *(const f32x4*)&dM[cb + m * 16 + rg];
  }
  __syncthreads();

  f32x4 acc[4][4];

  // ---- pass A: pre0^T; sp -> spt (vector b64 stores); tr0 ----
  mmT(z0t, W1b, l15, kof, cb, acc);
  {
    float p[4] = {0.f, 0.f, 0.f, 0.f};
    #pragma unroll
    for (int m = 0; m < 4; ++m)
      #pragma unroll
      for (int n = 0; n < 4; ++n) {
        s16x4 spv;
        #pragma unroll
        for (int r = 0; r < 4; ++r) {
          float pre = acc[m][n][r] + b1v[m][r];
          float e = __expf(-fabsf(pre));
          float rc = __fdividef(1.f, 1.f + e);
          p[n] += ((pre >= 0.f) ? rc : e * rc) * dmv[m][r];
          spv[r] = (short)f2bf(fmaxf(pre, 0.f) + __logf(1.f + e));
        }
        int token = n * 16 + l15;
        int colb = (cb + m * 16 + rg) * 2;
        *(s16x4*)((char*)spt + token * 512 + (colb ^ ((token & 7) << 4))) = spv;
      }
    #pragma unroll
    for (int n = 0; n < 4; ++n) {
      p[n] += __shfl_xor(p[n], 16);
      p[n] += __shfl_xor(p[n], 32);
    }
    if (lane < 16)
      #pragma unroll
      for (int n = 0; n < 4; ++n) trs[wv][n * 16 + l15] = p[n];
  }
  __syncthreads();

  // ---- pass B: f0^T; z1 = z0 + 0.5*f0 (vector b64 rmw into z0t) ----
  mmT(spt, W2b, l15, kof, cb, acc);
  {
    f32x4 b2v[4];
    #pragma unroll
    for (int m = 0; m < 4; ++m) b2v[m] = *(const f32x4*)&b2[cb + m * 16 + rg];
    #pragma unroll
    for (int m = 0; m < 4; ++m)
      #pragma unroll
      for (int n = 0; n < 4; ++n) {
        int token = n * 16 + l15;
        int colb = (cb + m * 16 + rg) * 2;
        char* zp = (char*)z0t + token * 512 + (colb ^ ((token & 7) << 4));
        s16x4 zv = *(s16x4*)zp;
        s16x4 ov;
        #pragma unroll
        for (int r = 0; r < 4; ++r) {
          float z0v = bf2f((unsigned short)zv[r]);
          ov[r] = (short)f2bf(z0v + 0.5f * (acc[m][n][r] + b2v[m][r]));
        }
        *(s16x4*)zp = ov;   // cell owned by this lane
      }
  }
  __syncthreads();

  // ---- pass C: pre1^T; tr1 ----
  mmT(z0t, W1b, l15, kof, cb, acc);
  {
    f32x4 bcv[4];
    #pragma unroll
    for (int m = 0; m < 4; ++m) {
      f32x4 wt = *(const f32x4*)&w1t[cb + m * 16 + rg];
      bcv[m] = b1v[m] + 0.5f * wt;
    }
    float p[4] = {0.f, 0.f, 0.f, 0.f};
    #pragma unroll
    for (int m = 0; m < 4; ++m)
      #pragma unroll
      for (int n = 0; n < 4; ++n)
        #pragma unroll
        for (int r = 0; r < 4; ++r) {
          float pre = acc[m][n][r] + bcv[m][r];
          float e = __expf(-fabsf(pre));
          float rc = __fdividef(1.f, 1.f + e);
          p[n] += ((pre >= 0.f) ? rc : e * rc) * dmv[m][r];
        }
    #pragma unroll
    for (int n = 0; n < 4; ++n) {
      p[n] += __shfl_xor(p[n], 16);
      p[n] += __shfl_xor(p[n], 32);
    }
    if (lane < 16)
      #pragma unroll
      for (int n = 0; n < 4; ++n) trs[wv][n * 16 + l15] += p[n];
  }
  __syncthreads();

  if (tid < 64) {
    float t = trs[0][tid] + trs[1][tid] + trs[2][tid] + trs[3][tid];
    cbias[tokbase + tid] += 0.5f * t;
  }
}

// ---------------- big log-prob GEMM ----------------
// Tile 128 h-rows x 64 tokens, 32 KB LDS -> 4 blocks/CU (16 waves/CU).
// rr = bid&7 pins a row-stripe per XCD (write-boundary merge in its L2,
// hb stripe L1-hot); tc = bid>>3 walks tokens left->right per XCD.
__global__ __launch_bounds__(256) void logp_kernel(
    const short* __restrict__ hb, const short* __restrict__ zb,
    const float* __restrict__ hnorm, const float* __restrict__ cbias,
    float* __restrict__ out) {
  __shared__ char smem[32768];
  short* Bz = (short*)smem;
  const int bid = blockIdx.x;   // 6288 = 786 * 8
  const int rr = bid & 7;
  const int tc = bid >> 3;
  const int tid = threadIdx.x;
  const int lane = tid & 63, wv = tid >> 6;
  const int l15 = lane & 15, rg = (lane >> 4) * 4, kof = (lane >> 4) * 8;

  // stage B tile (64 tokens, pre-swizzled rows): 32 KB linear copy
  {
    const char* bsrc = (const char*)(zb + (size_t)tc * 64 * 256);
    #pragma unroll
    for (int it = 0; it < 8; ++it) {
      int uoff = wv * 8192 + it * 1024;
      gload16(bsrc + uoff + lane * 16, smem + uoff);
    }
  }
  __syncthreads();

  const f32x4 vz = {0.f, 0.f, 0.f, 0.f};
  f32x4 acc[2][4];
  #pragma unroll
  for (int m = 0; m < 2; ++m)
    #pragma unroll
    for (int n = 0; n < 4; ++n) acc[m][n] = vz;

  const int arow0 = rr * 128 + wv * 32;
  #pragma unroll
  for (int s = 0; s < 8; ++s) {
    int k0 = s * 32 + kof;
    int ks = k0 ^ ((l15 & 7) << 3);
    bf16x8 a[2];
    #pragma unroll
    for (int m = 0; m < 2; ++m)
      a[m] = *(const bf16x8*)&hb[(arow0 + m * 16 + l15) * 256 + k0];  // linear
    #pragma unroll
    for (int n = 0; n < 4; ++n) {
      bf16x8 b = *(const bf16x8*)&Bz[(n * 16 + l15) * 256 + ks];
      #pragma unroll
      for (int m = 0; m < 2; ++m) acc[m][n] = MFMA16(a[m], b, acc[m][n]);
    }
  }
  __syncthreads();  // Bz reads done; overlay transpose patches

  // wave-private 16x68 f32 patch (4352 B each, inside the 32 KB overlay)
  float* patch = (float*)(smem + wv * 4352);
  const int l4 = lane & 15, lr4 = lane >> 4;
  #pragma unroll
  for (int m = 0; m < 2; ++m) {
    #pragma unroll
    for (int n = 0; n < 4; ++n)
      #pragma unroll
      for (int r = 0; r < 4; ++r)
        patch[(rg + r) * 68 + n * 16 + l15] = acc[m][n][r];
    asm volatile("s_waitcnt lgkmcnt(0)" ::: "memory");
    #pragma unroll
    for (int q = 0; q < 4; ++q) {
      int lrow = q * 4 + lr4;
      int gr = rr * 128 + wv * 32 + m * 16 + lrow;
      int gt = tc * 64 + l4 * 4;
      f32x4 v = *(const f32x4*)&patch[lrow * 68 + l4 * 4];
      float hn = hnorm[gr];
      f32x4 cb4 = *(const f32x4*)&cbias[gt];
      #pragma unroll
      for (int c = 0; c < 4; ++c) v[c] += cb4[c] - 0.5f * hn;
      float* op = out + (size_t)gr * NTOKEN + gt;
      if (gt + 4 <= NTOKEN) {
        *(f32x4u*)op = v;
      } else {
        #pragma unroll
        for (int c = 0; c < 4; ++c)
          if (gt + c < NTOKEN) op[c] = v[c];
      }
    }
    asm volatile("s_waitcnt lgkmcnt(0)" ::: "memory");
  }
}

// ---------------- launcher ----------------
extern "C" void kernel_launch(void* const* d_in, const int* in_sizes, int n_in,
                              void* d_out, int out_size, void* d_ws, size_t ws_size,
                              hipStream_t stream) {
  const float* h   = (const float*)d_in[0];
  const float* emb = (const float*)d_in[1];
  const float* W1x = (const float*)d_in[2];
  const float* w1t = (const float*)d_in[3];
  const float* b1  = (const float*)d_in[4];
  const float* W2  = (const float*)d_in[5];
  const float* b2  = (const float*)d_in[6];
  float* out = (float*)d_out;

  char* ws = (char*)d_ws;
  short* hb    = (short*)(ws + HB_OFF);
  short* zb    = (short*)(ws + ZB_OFF);
  float* hnorm = (float*)(ws + HN_OFF);
  float* cbias = (float*)(ws + CB_OFF);
  float* dM    = (float*)(ws + DM_OFF);
  short* W1b   = (short*)(ws + W1B_OFF);
  short* W2b   = (short*)(ws + W2B_OFF);

  prep_all<<<160 + NTOK_PAD / 32, 256, 0, stream>>>(h, emb, W1x, W2, hb, hnorm,
                                                    zb, cbias, W1b, W2b, dM);
  cnf_fused<<<NTOK_PAD / 64, 256, 0, stream>>>(zb, W1b, W2b, dM, w1t, b1, b2,
                                               cbias);
  logp_kernel<<<786 * 8, 256, 0, stream>>>(hb, zb, hnorm, cbias, out);
}

// Round 5
// 191.719 us; speedup vs baseline: 1.8061x; 1.0298x over previous
//
#include <hip/hip_runtime.h>

#define NTOKEN 50257
#define NTOK_PAD 50304   // 786 * 64
#define SB 1024
#define C_LOG2PI 235.2482644909f  // 0.5 * 256 * log(2*pi)

typedef __attribute__((ext_vector_type(8))) short bf16x8;
typedef __attribute__((ext_vector_type(4))) short s16x4;
typedef __attribute__((ext_vector_type(4))) float f32x4;
typedef float f32x4u __attribute__((ext_vector_type(4), aligned(4)));

#define MFMA16(a, b, c) __builtin_amdgcn_mfma_f32_16x16x32_bf16((a), (b), (c), 0, 0, 0)

__device__ __forceinline__ unsigned short f2bf(float f) {
  unsigned int u = __float_as_uint(f);
  u += 0x7fffu + ((u >> 16) & 1u);   // round-to-nearest-even
  return (unsigned short)(u >> 16);
}
__device__ __forceinline__ float bf2f(unsigned short s) {
  return __uint_as_float(((unsigned int)s) << 16);
}
__device__ __forceinline__ void gload16(const void* g, void* l) {
  __builtin_amdgcn_global_load_lds(
      (const __attribute__((address_space(1))) unsigned int*)g,
      (__attribute__((address_space(3))) unsigned int*)l, 16, 0, 0);
}

// ---------------- workspace layout (bytes) ----------------
#define HB_OFF   0u            // 1024*256*2  = 524288 (linear)
#define ZB_OFF   524288u       // 50304*256*2 = 25755648 (pre-swizzled rows)
#define HN_OFF   26279936u     // 1024*4
#define CB_OFF   26284032u     // 50304*4
#define DM_OFF   26485248u     // 256*4
#define W1B_OFF  26486272u     // 65536*2
#define W2B_OFF  26617344u     // 65536*2  (end = 26748416)

// ---------------- small prep: h, weights, diag ----------------
// grid = 32 (h) + 64 (conv_w) + 64 (diag) = 160 blocks x 256
__global__ __launch_bounds__(256) void prep_all(
    const float* __restrict__ h, const float* __restrict__ W1x,
    const float* __restrict__ W2, short* __restrict__ hb,
    float* __restrict__ hnorm, short* __restrict__ W1b,
    short* __restrict__ W2b, float* __restrict__ dM) {
  const int bid = blockIdx.x;
  const int tid = threadIdx.x;
  if (bid < 32) {
    // ---- h -> linear bf16 + norms ----
    int row = bid * 32 + (tid >> 3);
    int c0 = (tid & 7) * 32;
    float ss = 0.f;
    #pragma unroll
    for (int g = 0; g < 4; ++g) {
      int c = c0 + g * 8;
      const float4* p = (const float4*)&h[row * 256 + c];
      float4 x = p[0], y = p[1];
      float v[8] = {x.x, x.y, x.z, x.w, y.x, y.y, y.z, y.w};
      bf16x8 o;
      #pragma unroll
      for (int j = 0; j < 8; ++j) { ss += v[j] * v[j]; o[j] = (short)f2bf(v[j]); }
      *(bf16x8*)&hb[row * 256 + c] = o;
    }
    ss += __shfl_xor(ss, 1); ss += __shfl_xor(ss, 2); ss += __shfl_xor(ss, 4);
    if ((tid & 7) == 0) hnorm[row] = ss;
  } else if (bid < 96) {
    // ---- W1x, W2 -> bf16 ----
    int base = ((bid - 32) * 256 + tid) * 4;
    float4 a = *(const float4*)&W1x[base];
    short4 o1;
    o1.x = (short)f2bf(a.x); o1.y = (short)f2bf(a.y);
    o1.z = (short)f2bf(a.z); o1.w = (short)f2bf(a.w);
    *(short4*)&W1b[base] = o1;
    float4 b = *(const float4*)&W2[base];
    short4 o2;
    o2.x = (short)f2bf(b.x); o2.y = (short)f2bf(b.y);
    o2.z = (short)f2bf(b.z); o2.w = (short)f2bf(b.w);
    *(short4*)&W2b[base] = o2;
  } else {
    // ---- dM[j] = sum_i W1x[j,i] * W2[i,j] ----
    int j = (bid - 96) * 4 + (tid >> 6);
    int lane = tid & 63;
    float s = 0.f;
    #pragma unroll
    for (int t = 0; t < 4; ++t) {
      int i = lane + t * 64;
      s += W1x[j * 256 + i] * W2[i * 256 + j];
    }
    s += __shfl_xor(s, 1); s += __shfl_xor(s, 2); s += __shfl_xor(s, 4);
    s += __shfl_xor(s, 8); s += __shfl_xor(s, 16); s += __shfl_xor(s, 32);
    if (lane == 0) dM[j] = s;
  }
}

// ---------------- fused CNF + z-prep (operand-swapped MFMA) ----------------
// accT[m][n] = MFMA16(Wfrag[m], Tfrag[n]) -> D[wcol][token]:
//   wcol = cb + m*16 + rg + r (contiguous in r), token = n*16 + l15.
// T = LDS tile, rows = tokens (XOR-swizzled 16B groups); W = global, linear.
__device__ __forceinline__ void mmT(const short* T, const short* __restrict__ W,
                                    int l15, int kof, int cb, f32x4 acc[4][4]) {
  const f32x4 vz = {0.f, 0.f, 0.f, 0.f};
  #pragma unroll
  for (int m = 0; m < 4; ++m)
    #pragma unroll
    for (int n = 0; n < 4; ++n) acc[m][n] = vz;
  #pragma unroll
  for (int s = 0; s < 8; ++s) {
    int k0 = s * 32 + kof;
    int ks = k0 ^ ((l15 & 7) << 3);
    bf16x8 w[4], z[4];
    #pragma unroll
    for (int m = 0; m < 4; ++m)
      w[m] = *(const bf16x8*)&W[(cb + m * 16 + l15) * 256 + k0];
    #pragma unroll
    for (int n = 0; n < 4; ++n)
      z[n] = *(const bf16x8*)&T[(n * 16 + l15) * 256 + ks];
    #pragma unroll
    for (int m = 0; m < 4; ++m)
      #pragma unroll
      for (int n = 0; n < 4; ++n) acc[m][n] = MFMA16(w[m], z[n], acc[m][n]);
  }
}

__global__ __launch_bounds__(256) void cnf_fused(
    const float* __restrict__ emb, const short* __restrict__ W1b,
    const short* __restrict__ W2b, const float* __restrict__ dM,
    const float* __restrict__ w1t, const float* __restrict__ b1,
    const float* __restrict__ b2, short* __restrict__ zb,
    float* __restrict__ cbias) {
  __shared__ short z0t[64 * 256];   // 32 KB: z0, then z1
  __shared__ short spt[64 * 256];   // 32 KB: softplus(pre0)
  __shared__ float trs[4][64];
  __shared__ float znl[64];
  const int tid = threadIdx.x;
  const int lane = tid & 63, wv = tid >> 6;
  const int l15 = lane & 15, rg = (lane >> 4) * 4, kof = (lane >> 4) * 8;
  const int cb = wv * 64;
  const int tokbase = blockIdx.x * 64;

  // ---- stage z0: read emb fp32, convert, swizzled LDS + global zb, norms ----
  {
    int row = tid >> 2;           // 64 rows, 4 threads per row
    int c0 = (tid & 3) * 64;      // 64 floats each
    int gtok = tokbase + row;
    bool ok = gtok < NTOKEN;
    float ss = 0.f;
    #pragma unroll
    for (int g = 0; g < 8; ++g) {
      int c = c0 + g * 8;
      float v[8];
      if (ok) {
        const float4* p = (const float4*)&emb[(size_t)gtok * 256 + c];
        float4 x = p[0], y = p[1];
        v[0] = x.x; v[1] = x.y; v[2] = x.z; v[3] = x.w;
        v[4] = y.x; v[5] = y.y; v[6] = y.z; v[7] = y.w;
      } else {
        #pragma unroll
        for (int j = 0; j < 8; ++j) v[j] = 0.f;
      }
      bf16x8 o;
      #pragma unroll
      for (int j = 0; j < 8; ++j) { ss += v[j] * v[j]; o[j] = (short)f2bf(v[j]); }
      int blk = (c >> 3) ^ (row & 7);
      *(bf16x8*)&z0t[row * 256 + blk * 8] = o;
      *(bf16x8*)&zb[(size_t)gtok * 256 + blk * 8] = o;
    }
    ss += __shfl_xor(ss, 1); ss += __shfl_xor(ss, 2);
    if ((tid & 3) == 0) znl[row] = ss;
  }
  // per-lane wcol-quad constants (vector loads)
  f32x4 b1v[4], dmv[4];
  #pragma unroll
  for (int m = 0; m < 4; ++m) {
    b1v[m] = *(const f32x4*)&b1[cb + m * 16 + rg];
    dmv[m] = *(const f32x4*)&dM[cb + m * 16 + rg];
  }
  __syncthreads();

  f32x4 acc[4][4];

  // ---- pass A: pre0^T; sp -> spt (b64 stores); tr0 ----
  mmT(z0t, W1b, l15, kof, cb, acc);
  {
    float p[4] = {0.f, 0.f, 0.f, 0.f};
    #pragma unroll
    for (int m = 0; m < 4; ++m)
      #pragma unroll
      for (int n = 0; n < 4; ++n) {
        s16x4 spv;
        #pragma unroll
        for (int r = 0; r < 4; ++r) {
          float pre = acc[m][n][r] + b1v[m][r];
          float e = __expf(-fabsf(pre));
          float rc = __fdividef(1.f, 1.f + e);
          p[n] += ((pre >= 0.f) ? rc : e * rc) * dmv[m][r];
          spv[r] = (short)f2bf(fmaxf(pre, 0.f) + __logf(1.f + e));
        }
        int token = n * 16 + l15;
        int colb = (cb + m * 16 + rg) * 2;
        *(s16x4*)((char*)spt + token * 512 + (colb ^ ((token & 7) << 4))) = spv;
      }
    #pragma unroll
    for (int n = 0; n < 4; ++n) {
      p[n] += __shfl_xor(p[n], 16);
      p[n] += __shfl_xor(p[n], 32);
    }
    if (lane < 16)
      #pragma unroll
      for (int n = 0; n < 4; ++n) trs[wv][n * 16 + l15] = p[n];
  }
  __syncthreads();

  // ---- pass B: f0^T; z1 = z0 + 0.5*f0 (b64 rmw into z0t) ----
  mmT(spt, W2b, l15, kof, cb, acc);
  {
    f32x4 b2v[4];
    #pragma unroll
    for (int m = 0; m < 4; ++m) b2v[m] = *(const f32x4*)&b2[cb + m * 16 + rg];
    #pragma unroll
    for (int m = 0; m < 4; ++m)
      #pragma unroll
      for (int n = 0; n < 4; ++n) {
        int token = n * 16 + l15;
        int colb = (cb + m * 16 + rg) * 2;
        char* zp = (char*)z0t + token * 512 + (colb ^ ((token & 7) << 4));
        s16x4 zv = *(s16x4*)zp;
        s16x4 ov;
        #pragma unroll
        for (int r = 0; r < 4; ++r) {
          float z0v = bf2f((unsigned short)zv[r]);
          ov[r] = (short)f2bf(z0v + 0.5f * (acc[m][n][r] + b2v[m][r]));
        }
        *(s16x4*)zp = ov;   // cell owned by this lane
      }
  }
  __syncthreads();

  // ---- pass C: pre1^T; tr1 ----
  mmT(z0t, W1b, l15, kof, cb, acc);
  {
    f32x4 bcv[4];
    #pragma unroll
    for (int m = 0; m < 4; ++m) {
      f32x4 wt = *(const f32x4*)&w1t[cb + m * 16 + rg];
      bcv[m] = b1v[m] + 0.5f * wt;
    }
    float p[4] = {0.f, 0.f, 0.f, 0.f};
    #pragma unroll
    for (int m = 0; m < 4; ++m)
      #pragma unroll
      for (int n = 0; n < 4; ++n)
        #pragma unroll
        for (int r = 0; r < 4; ++r) {
          float pre = acc[m][n][r] + bcv[m][r];
          float e = __expf(-fabsf(pre));
          float rc = __fdividef(1.f, 1.f + e);
          p[n] += ((pre >= 0.f) ? rc : e * rc) * dmv[m][r];
        }
    #pragma unroll
    for (int n = 0; n < 4; ++n) {
      p[n] += __shfl_xor(p[n], 16);
      p[n] += __shfl_xor(p[n], 32);
    }
    if (lane < 16)
      #pragma unroll
      for (int n = 0; n < 4; ++n) trs[wv][n * 16 + l15] += p[n];
  }
  __syncthreads();

  if (tid < 64) {
    float t = trs[0][tid] + trs[1][tid] + trs[2][tid] + trs[3][tid];
    cbias[tokbase + tid] = -0.5f * znl[tid] - C_LOG2PI + 0.5f * t;
  }
}

// ---------------- big log-prob GEMM ----------------
// Block: 256 h-rows x 64 tokens (4 waves x 64 rows), 32 KB LDS -> 4 blocks/CU.
// B-tile reuse 8 B LDS per output (2x round 4). XCD scheme: 4 row-stripes x
// 2 token-halves; xcd = bid&7 owns (stripe = xcd&3, half = xcd>>2) and walks
// its token range contiguously -> write-boundary lines merge in its L2.
__global__ __launch_bounds__(256) void logp_kernel(
    const short* __restrict__ hb, const short* __restrict__ zb,
    const float* __restrict__ hnorm, const float* __restrict__ cbias,
    float* __restrict__ out) {
  __shared__ char smem[32768];
  short* Bz = (short*)smem;
  const int bid = blockIdx.x;   // 3144 = 393 * 8
  const int xcd = bid & 7;
  const int tc = (bid >> 3) + (xcd >> 2) * 393;   // token tile [0,786)
  const int row0 = (xcd & 3) * 256;
  const int tid = threadIdx.x;
  const int lane = tid & 63, wv = tid >> 6;
  const int l15 = lane & 15, rg = (lane >> 4) * 4, kof = (lane >> 4) * 8;

  // stage B tile (64 tokens, pre-swizzled rows): 32 KB linear copy
  {
    const char* bsrc = (const char*)(zb + (size_t)tc * 64 * 256);
    #pragma unroll
    for (int it = 0; it < 8; ++it) {
      int uoff = wv * 8192 + it * 1024;
      gload16(bsrc + uoff + lane * 16, smem + uoff);
    }
  }
  __syncthreads();

  const f32x4 vz = {0.f, 0.f, 0.f, 0.f};
  f32x4 acc[4][4];
  #pragma unroll
  for (int m = 0; m < 4; ++m)
    #pragma unroll
    for (int n = 0; n < 4; ++n) acc[m][n] = vz;

  const int arow0 = row0 + wv * 64;
  #pragma unroll
  for (int s = 0; s < 8; ++s) {
    int k0 = s * 32 + kof;
    int ks = k0 ^ ((l15 & 7) << 3);
    bf16x8 a[4];
    #pragma unroll
    for (int m = 0; m < 4; ++m)
      a[m] = *(const bf16x8*)&hb[(arow0 + m * 16 + l15) * 256 + k0];  // linear
    #pragma unroll
    for (int n = 0; n < 4; ++n) {
      bf16x8 b = *(const bf16x8*)&Bz[(n * 16 + l15) * 256 + ks];
      #pragma unroll
      for (int m = 0; m < 4; ++m) acc[m][n] = MFMA16(a[m], b, acc[m][n]);
    }
  }
  __syncthreads();  // Bz reads done; overlay transpose patches

  // wave-private 16x68 f32 patch (4352 B each, inside the 32 KB overlay)
  float* patch = (float*)(smem + wv * 4352);
  const int l4 = lane & 15, lr4 = lane >> 4;
  #pragma unroll
  for (int m = 0; m < 4; ++m) {
    #pragma unroll
    for (int n = 0; n < 4; ++n)
      #pragma unroll
      for (int r = 0; r < 4; ++r)
        patch[(rg + r) * 68 + n * 16 + l15] = acc[m][n][r];
    asm volatile("s_waitcnt lgkmcnt(0)" ::: "memory");
    #pragma unroll
    for (int q = 0; q < 4; ++q) {
      int lrow = q * 4 + lr4;
      int gr = arow0 + m * 16 + lrow;
      int gt = tc * 64 + l4 * 4;
      f32x4 v = *(const f32x4*)&patch[lrow * 68 + l4 * 4];
      float hn = hnorm[gr];
      f32x4 cb4 = *(const f32x4*)&cbias[gt];
      #pragma unroll
      for (int c = 0; c < 4; ++c) v[c] += cb4[c] - 0.5f * hn;
      float* op = out + (size_t)gr * NTOKEN + gt;
      if (gt + 4 <= NTOKEN) {
        *(f32x4u*)op = v;
      } else {
        #pragma unroll
        for (int c = 0; c < 4; ++c)
          if (gt + c < NTOKEN) op[c] = v[c];
      }
    }
    asm volatile("s_waitcnt lgkmcnt(0)" ::: "memory");
  }
}

// ---------------- launcher ----------------
extern "C" void kernel_launch(void* const* d_in, const int* in_sizes, int n_in,
                              void* d_out, int out_size, void* d_ws, size_t ws_size,
                              hipStream_t stream) {
  const float* h   = (const float*)d_in[0];
  const float* emb = (const float*)d_in[1];
  const float* W1x = (const float*)d_in[2];
  const float* w1t = (const float*)d_in[3];
  const float* b1  = (const float*)d_in[4];
  const float* W2  = (const float*)d_in[5];
  const float* b2  = (const float*)d_in[6];
  float* out = (float*)d_out;

  char* ws = (char*)d_ws;
  short* hb    = (short*)(ws + HB_OFF);
  short* zb    = (short*)(ws + ZB_OFF);
  float* hnorm = (float*)(ws + HN_OFF);
  float* cbias = (float*)(ws + CB_OFF);
  float* dM    = (float*)(ws + DM_OFF);
  short* W1b   = (short*)(ws + W1B_OFF);
  short* W2b   = (short*)(ws + W2B_OFF);

  prep_all<<<160, 256, 0, stream>>>(h, W1x, W2, hb, hnorm, W1b, W2b, dM);
  cnf_fused<<<NTOK_PAD / 64, 256, 0, stream>>>(emb, W1b, W2b, dM, w1t, b1, b2,
                                               zb, cbias);
  logp_kernel<<<393 * 8, 256, 0, stream>>>(hb, zb, hnorm, cbias, out);
}